// Round 9
// baseline (2080.985 us; speedup 1.0000x reference)
//
#include <hip/hip_runtime.h>
#include <hip/hip_bf16.h>
#include <stdint.h>

// Problem constants (fixed by setup_inputs)
#define BB 8
#define NN 16384
#define GG 1024
#define SS 32
#define BN (BB*NN)          // 131072

// Output offsets (elements, float32)
#define OFF_SIDX 0
#define OFF_SN   8192
#define OFF_SXYZ 770048     // 8192 + 8192*31*3
#define OFF_ORD  794624     // + 24576
#define OFF_INV  827392     // + 32768

// Workspace offsets (bytes)
#define WS_SIDX 0                    // int[8192]
#define WS_KNN  32768                // int[8192*32] = 1 MB

// DPP u32 max merge (fuses to v_max_u32_dpp). old=v, bound_ctrl=false =>
// lanes without a valid source keep v (idempotent merge).
template<int CTRL, int RM, int BM>
static __device__ __forceinline__ unsigned dpp_umax(unsigned v) {
    unsigned o = (unsigned)__builtin_amdgcn_update_dpp((int)v, (int)v, CTRL, RM, BM, false);
    return o > v ? o : v;
}

// DPP u64 min merge.
template<int CTRL, int RM, int BM>
static __device__ __forceinline__ uint64_t dpp_umin64(uint64_t v) {
    unsigned lo = (unsigned)v, hi = (unsigned)(v >> 32);
    unsigned olo = (unsigned)__builtin_amdgcn_update_dpp((int)lo, (int)lo, CTRL, RM, BM, false);
    unsigned ohi = (unsigned)__builtin_amdgcn_update_dpp((int)hi, (int)hi, CTRL, RM, BM, false);
    uint64_t o = ((uint64_t)ohi << 32) | olo;
    return o < v ? o : v;
}

// full-wave u64 min, result valid in lane 63
static __device__ __forceinline__ uint64_t wave_umin64(uint64_t v) {
    v = dpp_umin64<0x111, 0xf, 0xf>(v);   // row_shr:1
    v = dpp_umin64<0x112, 0xf, 0xf>(v);   // row_shr:2
    v = dpp_umin64<0x114, 0xf, 0xf>(v);   // row_shr:4
    v = dpp_umin64<0x118, 0xf, 0xf>(v);   // row_shr:8
    v = dpp_umin64<0x142, 0xa, 0xf>(v);   // row_bcast:15 -> rows 1,3
    v = dpp_umin64<0x143, 0xc, 0xf>(v);   // row_bcast:31 -> rows 2,3
    return v;
}

// broadcast u64 from (uniform) lane sl
static __device__ __forceinline__ uint64_t rdlane64(uint64_t v, int sl) {
    unsigned lo = (unsigned)__builtin_amdgcn_readlane((int)(unsigned)v, sl);
    unsigned hi = (unsigned)__builtin_amdgcn_readlane((int)(unsigned)(v >> 32), sl);
    return ((uint64_t)hi << 32) | lo;
}

// Monotone float->u32 map: preserves IEEE float ordering even for negatives
// (d2 = (cc+pp)-2dot can round to tiny negatives; numpy orders them lowest).
static __device__ __forceinline__ unsigned mono(float f) {
    unsigned u = __float_as_uint(f);
    return u ^ (unsigned)((((int)u) >> 31) | (int)0x80000000u);
}

// ---------------------------------------------------------------------------
// 1) FPS: one block/batch, 1024 thr, 16 pts/thread. x,y state lives in LDS
//    (float2, lane-major: lane stride 8B = 2-way bank alias = free), read
//    back with ds_read_b64 each step — an explicit, un-rematerializable
//    fetch (the RA refused to keep 48 floats resident across 3 rounds of
//    hints; LDS makes the per-step cost deterministic). z[16]+dist[16] stay
//    in registers. Reduction skeleton identical to R3/R6/R7 (validated):
//    wave DPP value-max -> LDS -> block DPP max -> block-max holders
//    atomicMin packed p = t + e*1024 (exact numpy first-argmax).
// ---------------------------------------------------------------------------
extern __shared__ float2 fps_xy[];    // 16384 float2 = 128 KB dynamic LDS

__global__ __launch_bounds__(1024)
__attribute__((amdgpu_waves_per_eu(4, 4)))
void fps_kernel(const float* __restrict__ coord,
                int* __restrict__ ws_sidx,
                float* __restrict__ out) {
#pragma clang fp contract(off)
    const int b = blockIdx.x;
    const int t = threadIdx.x;
    const int base = b * NN;
    const int wave = t >> 6, lane = t & 63;

    float zr[16], dist[16];
#pragma unroll
    for (int j = 0; j < 16; j++) {
        int p = t + (j << 10);
        float2 xy;
        xy.x = coord[3*(base+p)];
        xy.y = coord[3*(base+p)+1];
        zr[j] = coord[3*(base+p)+2];
        fps_xy[p] = xy;               // own slot; barrier below publishes
        dist[j] = __builtin_inff();
    }

    __shared__ unsigned wv[16];       // per-wave max bits
    __shared__ unsigned win[2];       // packed winner p, double-buffered by parity

    if (t == 0) {
        ws_sidx[b*GG] = base;                 // selection 0 = index 0
        out[OFF_SIDX + b*GG] = (float)base;
        win[0] = 0xffffffffu; win[1] = 0xffffffffu;
    }
    // q0 = pts[0] (uniform scalar load)
    float qx = coord[3*base], qy = coord[3*base+1], qz = coord[3*base+2];
    __syncthreads();

    for (int g = 1; g < GG; g++) {
        const int s = g & 1;
        // ---- scan: dist = min(dist, |p-q|^2), bit-exact (no fma, left-assoc)
        //      xy streamed from LDS (own slots), z from registers
        unsigned lb = 0u;
#pragma unroll
        for (int j = 0; j < 16; j++) {
            float2 xy = fps_xy[t + (j << 10)];
            float dx = xy.x - qx, dy = xy.y - qy, dz = zr[j] - qz;
            float d  = (dx*dx + dy*dy) + dz*dz;
            float nd = fminf(dist[j], d);
            dist[j] = nd;
            unsigned nb = __float_as_uint(nd);   // nd >= +0: bits order == float order
            lb = nb > lb ? nb : lb;
        }
        // ---- wave max via DPP (value only; result in lane 63)
        unsigned r = lb;
        r = dpp_umax<0x111, 0xf, 0xf>(r);
        r = dpp_umax<0x112, 0xf, 0xf>(r);
        r = dpp_umax<0x114, 0xf, 0xf>(r);
        r = dpp_umax<0x118, 0xf, 0xf>(r);
        r = dpp_umax<0x142, 0xa, 0xf>(r);
        r = dpp_umax<0x143, 0xc, 0xf>(r);
        unsigned wmax = (unsigned)__builtin_amdgcn_readlane((int)r, 63);
        if (lane == 0) wv[wave] = wmax;
        __syncthreads();                      // B1: wv ready; win[s] reads of g-1 done
        if (t == 0) win[1 - s] = 0xffffffffu; // reset other slot for step g+1
        // ---- block max: 16 wave winners, 4-level DPP within rows of 16
        unsigned x = wv[lane & 15];
        x = dpp_umax<0x111, 0xf, 0xf>(x);
        x = dpp_umax<0x112, 0xf, 0xf>(x);
        x = dpp_umax<0x114, 0xf, 0xf>(x);
        x = dpp_umax<0x118, 0xf, 0xf>(x);
        unsigned bmax = (unsigned)__builtin_amdgcn_readlane((int)x, 15);
        // ---- claim: exact first-max index = min p, p = t + e*1024 (rare path)
        if (lb == bmax) {
            int e = 15;
#pragma unroll
            for (int jj = 15; jj >= 0; jj--) {
                if (__float_as_uint(dist[jj]) == bmax) e = jj;
            }
            atomicMin(&win[s], (unsigned)(t + (e << 10)));
        }
        __syncthreads();                      // B2: winner resolved
        unsigned pw = win[s];
        int sp = __builtin_amdgcn_readfirstlane((int)pw);
        if (t == 0) {
            ws_sidx[b*GG + g] = base + sp;
            out[OFF_SIDX + b*GG + g] = (float)(base + sp);
        }
        // uniform (scalar) reload of winner coords
        qx = coord[3*(base+sp)];
        qy = coord[3*(base+sp)+1];
        qz = coord[3*(base+sp)+2];
    }
}

// ---------------------------------------------------------------------------
// 2) kNN top-32: one wave per center, no LDS. Per-lane TOP-2 cache of packed
//    keys (mono(d2)<<14 | p): the scattered rescan of the winner's stripe
//    runs only when the winner's cache is empty (~7/32 rounds). mono() makes
//    key order == (d2 float order, index) lex == stable top_k semantics.
// ---------------------------------------------------------------------------
__global__ __launch_bounds__(64) void knn_kernel(const float* __restrict__ coord,
                                                 const int* __restrict__ ws_sidx,
                                                 int* __restrict__ ws_knn) {
#pragma clang fp contract(off)
    const int c = blockIdx.x;             // center 0..8191
    const int l = threadIdx.x;            // lane 0..63
    const int b = c >> 10;
    const int base = b * NN;
    const int sg = ws_sidx[c];            // global center index
    const float cx = coord[3*sg], cy = coord[3*sg+1], cz = coord[3*sg+2];
    const float cc = (cx*cx + cy*cy) + cz*cz;

    // phase 1: per-lane two smallest keys over stripe {l + 64*j}
    uint64_t k1 = ~0ull, k2 = ~0ull;
#pragma unroll 4
    for (int j = 0; j < 256; j++) {
        int p = l + (j << 6);
        float x = coord[3*(base+p)], y = coord[3*(base+p)+1], z = coord[3*(base+p)+2];
        float pp  = (x*x + y*y) + z*z;
        float dot = (cx*x + cy*y) + cz*z;
        float d2  = (cc + pp) - 2.0f*dot;             // ref formula exactly
        uint64_t key = (((uint64_t)mono(d2)) << 14) | (unsigned)p;
        if (key < k1)      { k2 = k1; k1 = key; }
        else if (key < k2) { k2 = key; }
    }

    uint64_t m0 = 0, m1 = 0, m2 = 0, m3 = 0;          // consumed bits, my stripe
    uint64_t cur = k1, nxt = k2;
    bool have_nxt = true;
    int res_p = 0;
    for (int k = 0; k < SS; k++) {
        // global argmin over per-lane current minima (value, then index)
        uint64_t wmin = wave_umin64(cur);
        uint64_t bkey = rdlane64(wmin, 63);           // scalar winner key
        const int bp = (int)(bkey & 16383u);          // winner point (scalar)
        const int w  = bp & 63;                       // winner lane / stripe
        const int e  = bp >> 6;                       // element within stripe
        if (l == k) res_p = bp;                       // lane k keeps k-th neighbor
        bool need_rescan = false;
        if (l == w) {                                 // mark consumed
            uint64_t bit = 1ull << (e & 63);
            int word = e >> 6;
            if      (word == 0) m0 |= bit;
            else if (word == 1) m1 |= bit;
            else if (word == 2) m2 |= bit;
            else                m3 |= bit;
            if (have_nxt) { cur = nxt; have_nxt = false; }
            else need_rescan = true;
        }
        if (__ballot(need_rescan)) {                  // wave-uniform rare path
            uint64_t w0 = rdlane64(m0, w), w1 = rdlane64(m1, w),
                     w2 = rdlane64(m2, w), w3 = rdlane64(m3, w);
            uint64_t best = ~0ull;
#pragma unroll
            for (int m = 0; m < 4; m++) {
                int e2 = l + (m << 6);
                uint64_t mw = (m == 0) ? w0 : ((m == 1) ? w1 : ((m == 2) ? w2 : w3));
                int p2 = w + (e2 << 6);
                float x = coord[3*(base+p2)], y = coord[3*(base+p2)+1], z = coord[3*(base+p2)+2];
                float pp  = (x*x + y*y) + z*z;
                float dot = (cx*x + cy*y) + cz*z;
                float d2  = (cc + pp) - 2.0f*dot;     // bit-exact recompute
                uint64_t key = (((uint64_t)mono(d2)) << 14) | (unsigned)p2;
                bool cons = (mw >> l) & 1ull;
                if (!cons && key < best) best = key;
            }
            best = wave_umin64(best);
            uint64_t rk = rdlane64(best, 63);
            if (l == w) cur = rk;                     // refreshed stripe-min
        }
    }
    if (l < SS) ws_knn[c * SS + l] = res_p;           // local point index
}

// ---------------------------------------------------------------------------
// 3) s_xyz gather
// ---------------------------------------------------------------------------
__global__ void sxyz_kernel(const float* __restrict__ coord,
                            const int* __restrict__ ws_sidx,
                            float* __restrict__ out) {
    int t = blockIdx.x * blockDim.x + threadIdx.x;
    if (t < 8192*3) {
        int i = t / 3, cmp = t - 3*i;
        out[OFF_SXYZ + t] = coord[3*ws_sidx[i] + cmp];
    }
}

// ---------------------------------------------------------------------------
// 4) s_n = coord[knn[1..31]] - center
// ---------------------------------------------------------------------------
__global__ void sn_kernel(const float* __restrict__ coord,
                          const int* __restrict__ ws_sidx,
                          const int* __restrict__ ws_knn,
                          float* __restrict__ out) {
#pragma clang fp contract(off)
    int t = blockIdx.x * blockDim.x + threadIdx.x;
    if (t < 8192*31*3) {
        int cmp = t % 3; int rem = t / 3;
        int j = rem % 31; int i = rem / 31;
        int b = i >> 10;
        int nb = ws_knn[i*SS + j + 1];                // skip neighbor 0 (self)
        int gidx = b*NN + nb;
        float v = coord[3*gidx + cmp] - coord[3*ws_sidx[i] + cmp];
        out[OFF_SN + t] = v;
    }
}

// ---------------------------------------------------------------------------
// 5) stable argsort per code row: bitonic sort of (code<<13 | idx) in LDS
// ---------------------------------------------------------------------------
__global__ __launch_bounds__(1024) void sort_kernel(const int* __restrict__ ser,
                                                    const int* __restrict__ ws_sidx,
                                                    float* __restrict__ out) {
    __shared__ uint64_t keys[8192];                   // 64 KB
    const int r = blockIdx.x, t = threadIdx.x;
#pragma unroll
    for (int s = 0; s < 8; s++) {
        int i = t + (s << 10);
        uint32_t code = (uint32_t)ser[r * BN + ws_sidx[i]];   // < 2^30
        keys[i] = ((uint64_t)code << 13) | (uint32_t)i;       // unique keys => stable
    }
    __syncthreads();
    for (int k2 = 2; k2 <= 8192; k2 <<= 1) {
        for (int j = k2 >> 1; j > 0; j >>= 1) {
#pragma unroll 2
            for (int s = 0; s < 8; s++) {
                int i = t + (s << 10);
                int ixj = i ^ j;
                if (ixj > i) {
                    uint64_t a = keys[i], bq = keys[ixj];
                    bool up = ((i & k2) == 0);
                    if ((a > bq) == up) { keys[i] = bq; keys[ixj] = a; }
                }
            }
            __syncthreads();
        }
    }
    for (int s = 0; s < 8; s++) {
        int k = t + (s << 10);
        uint64_t key = keys[k];
        int i = (int)(key & 8191u);
        out[OFF_ORD + r*8192 + k] = (float)i;
        out[OFF_INV + r*8192 + i] = (float)k;
    }
}

// ---------------------------------------------------------------------------
extern "C" void kernel_launch(void* const* d_in, const int* in_sizes, int n_in,
                              void* d_out, int out_size, void* d_ws, size_t ws_size,
                              hipStream_t stream) {
    const float* coord = (const float*)d_in[0];
    const int*   ser   = (const int*)d_in[1];
    float* out = (float*)d_out;
    char* ws = (char*)d_ws;
    int* ws_sidx = (int*)(ws + WS_SIDX);
    int* ws_knn  = (int*)(ws + WS_KNN);

    // allow 128 KB dynamic LDS for fps (idempotent host call, capture-safe)
    hipFuncSetAttribute((const void*)fps_kernel,
                        hipFuncAttributeMaxDynamicSharedMemorySize, 131072);

    hipLaunchKernelGGL(fps_kernel,  dim3(BB),   dim3(1024), 131072, stream, coord, ws_sidx, out);
    hipLaunchKernelGGL(knn_kernel,  dim3(8192), dim3(64),   0, stream, coord, ws_sidx, ws_knn);
    hipLaunchKernelGGL(sxyz_kernel, dim3(96),   dim3(256),  0, stream, coord, ws_sidx, out);
    hipLaunchKernelGGL(sn_kernel,   dim3(2976), dim3(256),  0, stream, coord, ws_sidx, ws_knn, out);
    hipLaunchKernelGGL(sort_kernel, dim3(4),    dim3(1024), 0, stream, ser, ws_sidx, out);
}

// Round 10
// 1826.156 us; speedup vs baseline: 1.1395x; 1.1395x over previous
//
#include <hip/hip_runtime.h>
#include <hip/hip_bf16.h>
#include <stdint.h>

// Problem constants (fixed by setup_inputs)
#define BB 8
#define NN 16384
#define GG 1024
#define SS 32
#define BN (BB*NN)          // 131072

// Output offsets (elements, float32)
#define OFF_SIDX 0
#define OFF_SN   8192
#define OFF_SXYZ 770048     // 8192 + 8192*31*3
#define OFF_ORD  794624     // + 24576
#define OFF_INV  827392     // + 32768

// Workspace offsets (bytes)
#define WS_SIDX 0                    // int[8192]
#define WS_KNN  32768                // int[8192*32] = 1 MB

typedef float v2f __attribute__((ext_vector_type(2)));

static __device__ __forceinline__ v2f vmin2(v2f a, v2f b) {
    v2f r; r.x = fminf(a.x, b.x); r.y = fminf(a.y, b.y); return r;
}
static __device__ __forceinline__ v2f vmax2(v2f a, v2f b) {
    v2f r; r.x = fmaxf(a.x, b.x); r.y = fmaxf(a.y, b.y); return r;
}

// DPP u32 max merge (fuses to v_max_u32_dpp). old=v, bound_ctrl=false =>
// lanes without a valid source keep v (idempotent merge).
template<int CTRL, int RM, int BM>
static __device__ __forceinline__ unsigned dpp_umax(unsigned v) {
    unsigned o = (unsigned)__builtin_amdgcn_update_dpp((int)v, (int)v, CTRL, RM, BM, false);
    return o > v ? o : v;
}

// DPP u64 min merge.
template<int CTRL, int RM, int BM>
static __device__ __forceinline__ uint64_t dpp_umin64(uint64_t v) {
    unsigned lo = (unsigned)v, hi = (unsigned)(v >> 32);
    unsigned olo = (unsigned)__builtin_amdgcn_update_dpp((int)lo, (int)lo, CTRL, RM, BM, false);
    unsigned ohi = (unsigned)__builtin_amdgcn_update_dpp((int)hi, (int)hi, CTRL, RM, BM, false);
    uint64_t o = ((uint64_t)ohi << 32) | olo;
    return o < v ? o : v;
}

// full-wave u64 min, result valid in lane 63
static __device__ __forceinline__ uint64_t wave_umin64(uint64_t v) {
    v = dpp_umin64<0x111, 0xf, 0xf>(v);   // row_shr:1
    v = dpp_umin64<0x112, 0xf, 0xf>(v);   // row_shr:2
    v = dpp_umin64<0x114, 0xf, 0xf>(v);   // row_shr:4
    v = dpp_umin64<0x118, 0xf, 0xf>(v);   // row_shr:8
    v = dpp_umin64<0x142, 0xa, 0xf>(v);   // row_bcast:15 -> rows 1,3
    v = dpp_umin64<0x143, 0xc, 0xf>(v);   // row_bcast:31 -> rows 2,3
    return v;
}

// broadcast u64 from (uniform) lane sl
static __device__ __forceinline__ uint64_t rdlane64(uint64_t v, int sl) {
    unsigned lo = (unsigned)__builtin_amdgcn_readlane((int)(unsigned)v, sl);
    unsigned hi = (unsigned)__builtin_amdgcn_readlane((int)(unsigned)(v >> 32), sl);
    return ((uint64_t)hi << 32) | lo;
}

// Monotone float->u32 map: preserves IEEE float ordering even for negatives
// (d2 = (cc+pp)-2dot can round to tiny negatives; numpy orders them lowest).
static __device__ __forceinline__ unsigned mono(float f) {
    unsigned u = __float_as_uint(f);
    return u ^ (unsigned)((((int)u) >> 31) | (int)0x80000000u);
}

// ---------------------------------------------------------------------------
// 1) FPS: one block/batch, 1024 thr, 16 pts/thread as 8 float2 pairs.
//    ANTI-SINK restructure: dist is initialized against q0 in the PREAMBLE
//    (bit-exact: ref's first update is min(inf,d2)=d2), so every coord value
//    has a pre-loop use -> MachineSink cannot sink the 48 loads into the
//    g-loop -> values stay live in VGPRs (~90 < 128 budget @ waves_per_eu 4).
//    Loop order: argmax FIRST (on current dist), then update with the new
//    winner — same sequence as the reference shifted by one step.
//    Reduction skeleton = R3/R6/R7-validated: wave DPP value-max -> LDS ->
//    block DPP max -> block-max holders atomicMin packed p = t + e*1024
//    (exact numpy first-argmax).
// ---------------------------------------------------------------------------
__global__ __launch_bounds__(1024)
__attribute__((amdgpu_waves_per_eu(4, 4)))
void fps_kernel(const float* __restrict__ coord,
                int* __restrict__ ws_sidx,
                float* __restrict__ out) {
#pragma clang fp contract(off)
    const int b = blockIdx.x;
    const int t = threadIdx.x;
    const int base = b * NN;
    const int wave = t >> 6, lane = t & 63;

    // q0 = pts[0] (uniform scalar load)
    const float q0x = coord[3*base], q0y = coord[3*base+1], q0z = coord[3*base+2];

    // pair j covers point indices e=2j (x-slot) and e=2j+1 (y-slot), p = t + e*1024
    v2f px[8], py[8], pz[8], dist[8];
#pragma unroll
    for (int j = 0; j < 8; j++) {
        int pA = t + (j << 11);
        int pB = pA + 1024;
        px[j] = (v2f){coord[3*(base+pA)  ], coord[3*(base+pB)  ]};
        py[j] = (v2f){coord[3*(base+pA)+1], coord[3*(base+pB)+1]};
        pz[j] = (v2f){coord[3*(base+pA)+2], coord[3*(base+pB)+2]};
        // PREAMBLE USE of the coords: dist vs q0 (== ref's first update)
        v2f dx = px[j] - (v2f){q0x,q0x};
        v2f dy = py[j] - (v2f){q0y,q0y};
        v2f dz = pz[j] - (v2f){q0z,q0z};
        dist[j] = (dx*dx + dy*dy) + dz*dz;
    }

    __shared__ unsigned wv[16];       // per-wave max bits
    __shared__ unsigned win[2];       // packed winner p, double-buffered by parity

    if (t == 0) {
        ws_sidx[b*GG] = base;                 // selection 0 = index 0
        out[OFF_SIDX + b*GG] = (float)base;
        win[0] = 0xffffffffu; win[1] = 0xffffffffu;
    }
    __syncthreads();

    for (int g = 1; g < GG; g++) {
        const int s = g & 1;
        // ---- per-thread max of current dist (value only), pk tree
        //      (dists are sums of squares >= +0: u32 bit order == float order)
        v2f m01 = vmax2(dist[0], dist[1]);
        v2f m23 = vmax2(dist[2], dist[3]);
        v2f m45 = vmax2(dist[4], dist[5]);
        v2f m67 = vmax2(dist[6], dist[7]);
        v2f m07 = vmax2(vmax2(m01, m23), vmax2(m45, m67));
        float bvf = fmaxf(m07.x, m07.y);
        unsigned lb = __float_as_uint(bvf);   // local max as orderable bits
        // ---- wave max via DPP (value only; result in lane 63)
        unsigned r = lb;
        r = dpp_umax<0x111, 0xf, 0xf>(r);
        r = dpp_umax<0x112, 0xf, 0xf>(r);
        r = dpp_umax<0x114, 0xf, 0xf>(r);
        r = dpp_umax<0x118, 0xf, 0xf>(r);
        r = dpp_umax<0x142, 0xa, 0xf>(r);
        r = dpp_umax<0x143, 0xc, 0xf>(r);
        unsigned wmax = (unsigned)__builtin_amdgcn_readlane((int)r, 63);
        if (lane == 0) wv[wave] = wmax;
        __syncthreads();                      // B1: wv ready; win[s] reads of g-1 done
        if (t == 0) win[1 - s] = 0xffffffffu; // reset other slot for step g+1
        // ---- block max: 16 wave winners, 4-level DPP within rows of 16
        unsigned x = wv[lane & 15];
        x = dpp_umax<0x111, 0xf, 0xf>(x);
        x = dpp_umax<0x112, 0xf, 0xf>(x);
        x = dpp_umax<0x114, 0xf, 0xf>(x);
        x = dpp_umax<0x118, 0xf, 0xf>(x);
        unsigned bmax = (unsigned)__builtin_amdgcn_readlane((int)x, 15);
        // ---- claim: exact first-max index = min p, p = t + e*1024 (rare path)
        if (lb == bmax) {
            int e = 15;
#pragma unroll
            for (int jj = 15; jj >= 0; jj--) {
                float v = (jj & 1) ? dist[jj >> 1].y : dist[jj >> 1].x;
                if (__float_as_uint(v) == bmax) e = jj;
            }
            atomicMin(&win[s], (unsigned)(t + (e << 10)));
        }
        __syncthreads();                      // B2: winner resolved
        unsigned pw = win[s];
        int sp = __builtin_amdgcn_readfirstlane((int)pw);
        if (t == 0) {
            ws_sidx[b*GG + g] = base + sp;
            out[OFF_SIDX + b*GG + g] = (float)(base + sp);
        }
        // uniform (scalar) reload of winner coords
        float qx = coord[3*(base+sp)];
        float qy = coord[3*(base+sp)+1];
        float qz = coord[3*(base+sp)+2];
        // ---- update AFTER select: dist = min(dist, |p - q_g|^2), bit-exact
        //      (iteration g+1's argmax sees it; final update is dead work)
        v2f qvx = (v2f){qx,qx}, qvy = (v2f){qy,qy}, qvz = (v2f){qz,qz};
#pragma unroll
        for (int j = 0; j < 8; j++) {
            v2f dx = px[j] - qvx, dy = py[j] - qvy, dz = pz[j] - qvz;
            v2f d  = (dx*dx + dy*dy) + dz*dz;
            dist[j] = vmin2(dist[j], d);
        }
    }
}

// ---------------------------------------------------------------------------
// 2) kNN top-32: one wave per center, no LDS. Per-lane TOP-2 cache of packed
//    keys (mono(d2)<<14 | p): the scattered rescan of the winner's stripe
//    runs only when the winner's cache is empty (~7/32 rounds). mono() makes
//    key order == (d2 float order, index) lex == stable top_k semantics.
// ---------------------------------------------------------------------------
__global__ __launch_bounds__(64) void knn_kernel(const float* __restrict__ coord,
                                                 const int* __restrict__ ws_sidx,
                                                 int* __restrict__ ws_knn) {
#pragma clang fp contract(off)
    const int c = blockIdx.x;             // center 0..8191
    const int l = threadIdx.x;            // lane 0..63
    const int b = c >> 10;
    const int base = b * NN;
    const int sg = ws_sidx[c];            // global center index
    const float cx = coord[3*sg], cy = coord[3*sg+1], cz = coord[3*sg+2];
    const float cc = (cx*cx + cy*cy) + cz*cz;

    // phase 1: per-lane two smallest keys over stripe {l + 64*j}
    uint64_t k1 = ~0ull, k2 = ~0ull;
#pragma unroll 4
    for (int j = 0; j < 256; j++) {
        int p = l + (j << 6);
        float x = coord[3*(base+p)], y = coord[3*(base+p)+1], z = coord[3*(base+p)+2];
        float pp  = (x*x + y*y) + z*z;
        float dot = (cx*x + cy*y) + cz*z;
        float d2  = (cc + pp) - 2.0f*dot;             // ref formula exactly
        uint64_t key = (((uint64_t)mono(d2)) << 14) | (unsigned)p;
        if (key < k1)      { k2 = k1; k1 = key; }
        else if (key < k2) { k2 = key; }
    }

    uint64_t m0 = 0, m1 = 0, m2 = 0, m3 = 0;          // consumed bits, my stripe
    uint64_t cur = k1, nxt = k2;
    bool have_nxt = true;
    int res_p = 0;
    for (int k = 0; k < SS; k++) {
        // global argmin over per-lane current minima (value, then index)
        uint64_t wmin = wave_umin64(cur);
        uint64_t bkey = rdlane64(wmin, 63);           // scalar winner key
        const int bp = (int)(bkey & 16383u);          // winner point (scalar)
        const int w  = bp & 63;                       // winner lane / stripe
        const int e  = bp >> 6;                       // element within stripe
        if (l == k) res_p = bp;                       // lane k keeps k-th neighbor
        bool need_rescan = false;
        if (l == w) {                                 // mark consumed
            uint64_t bit = 1ull << (e & 63);
            int word = e >> 6;
            if      (word == 0) m0 |= bit;
            else if (word == 1) m1 |= bit;
            else if (word == 2) m2 |= bit;
            else                m3 |= bit;
            if (have_nxt) { cur = nxt; have_nxt = false; }
            else need_rescan = true;
        }
        if (__ballot(need_rescan)) {                  // wave-uniform rare path
            uint64_t w0 = rdlane64(m0, w), w1 = rdlane64(m1, w),
                     w2 = rdlane64(m2, w), w3 = rdlane64(m3, w);
            uint64_t best = ~0ull;
#pragma unroll
            for (int m = 0; m < 4; m++) {
                int e2 = l + (m << 6);
                uint64_t mw = (m == 0) ? w0 : ((m == 1) ? w1 : ((m == 2) ? w2 : w3));
                int p2 = w + (e2 << 6);
                float x = coord[3*(base+p2)], y = coord[3*(base+p2)+1], z = coord[3*(base+p2)+2];
                float pp  = (x*x + y*y) + z*z;
                float dot = (cx*x + cy*y) + cz*z;
                float d2  = (cc + pp) - 2.0f*dot;     // bit-exact recompute
                uint64_t key = (((uint64_t)mono(d2)) << 14) | (unsigned)p2;
                bool cons = (mw >> l) & 1ull;
                if (!cons && key < best) best = key;
            }
            best = wave_umin64(best);
            uint64_t rk = rdlane64(best, 63);
            if (l == w) cur = rk;                     // refreshed stripe-min
        }
    }
    if (l < SS) ws_knn[c * SS + l] = res_p;           // local point index
}

// ---------------------------------------------------------------------------
// 3) s_xyz gather
// ---------------------------------------------------------------------------
__global__ void sxyz_kernel(const float* __restrict__ coord,
                            const int* __restrict__ ws_sidx,
                            float* __restrict__ out) {
    int t = blockIdx.x * blockDim.x + threadIdx.x;
    if (t < 8192*3) {
        int i = t / 3, cmp = t - 3*i;
        out[OFF_SXYZ + t] = coord[3*ws_sidx[i] + cmp];
    }
}

// ---------------------------------------------------------------------------
// 4) s_n = coord[knn[1..31]] - center
// ---------------------------------------------------------------------------
__global__ void sn_kernel(const float* __restrict__ coord,
                          const int* __restrict__ ws_sidx,
                          const int* __restrict__ ws_knn,
                          float* __restrict__ out) {
#pragma clang fp contract(off)
    int t = blockIdx.x * blockDim.x + threadIdx.x;
    if (t < 8192*31*3) {
        int cmp = t % 3; int rem = t / 3;
        int j = rem % 31; int i = rem / 31;
        int b = i >> 10;
        int nb = ws_knn[i*SS + j + 1];                // skip neighbor 0 (self)
        int gidx = b*NN + nb;
        float v = coord[3*gidx + cmp] - coord[3*ws_sidx[i] + cmp];
        out[OFF_SN + t] = v;
    }
}

// ---------------------------------------------------------------------------
// 5) stable argsort per code row: bitonic sort of (code<<13 | idx) in LDS
// ---------------------------------------------------------------------------
__global__ __launch_bounds__(1024) void sort_kernel(const int* __restrict__ ser,
                                                    const int* __restrict__ ws_sidx,
                                                    float* __restrict__ out) {
    __shared__ uint64_t keys[8192];                   // 64 KB
    const int r = blockIdx.x, t = threadIdx.x;
#pragma unroll
    for (int s = 0; s < 8; s++) {
        int i = t + (s << 10);
        uint32_t code = (uint32_t)ser[r * BN + ws_sidx[i]];   // < 2^30
        keys[i] = ((uint64_t)code << 13) | (uint32_t)i;       // unique keys => stable
    }
    __syncthreads();
    for (int k2 = 2; k2 <= 8192; k2 <<= 1) {
        for (int j = k2 >> 1; j > 0; j >>= 1) {
#pragma unroll 2
            for (int s = 0; s < 8; s++) {
                int i = t + (s << 10);
                int ixj = i ^ j;
                if (ixj > i) {
                    uint64_t a = keys[i], bq = keys[ixj];
                    bool up = ((i & k2) == 0);
                    if ((a > bq) == up) { keys[i] = bq; keys[ixj] = a; }
                }
            }
            __syncthreads();
        }
    }
    for (int s = 0; s < 8; s++) {
        int k = t + (s << 10);
        uint64_t key = keys[k];
        int i = (int)(key & 8191u);
        out[OFF_ORD + r*8192 + k] = (float)i;
        out[OFF_INV + r*8192 + i] = (float)k;
    }
}

// ---------------------------------------------------------------------------
extern "C" void kernel_launch(void* const* d_in, const int* in_sizes, int n_in,
                              void* d_out, int out_size, void* d_ws, size_t ws_size,
                              hipStream_t stream) {
    const float* coord = (const float*)d_in[0];
    const int*   ser   = (const int*)d_in[1];
    float* out = (float*)d_out;
    char* ws = (char*)d_ws;
    int* ws_sidx = (int*)(ws + WS_SIDX);
    int* ws_knn  = (int*)(ws + WS_KNN);

    hipLaunchKernelGGL(fps_kernel,  dim3(BB),   dim3(1024), 0, stream, coord, ws_sidx, out);
    hipLaunchKernelGGL(knn_kernel,  dim3(8192), dim3(64),   0, stream, coord, ws_sidx, ws_knn);
    hipLaunchKernelGGL(sxyz_kernel, dim3(96),   dim3(256),  0, stream, coord, ws_sidx, out);
    hipLaunchKernelGGL(sn_kernel,   dim3(2976), dim3(256),  0, stream, coord, ws_sidx, ws_knn, out);
    hipLaunchKernelGGL(sort_kernel, dim3(4),    dim3(1024), 0, stream, ser, ws_sidx, out);
}

// Round 11
// 1811.769 us; speedup vs baseline: 1.1486x; 1.0079x over previous
//
#include <hip/hip_runtime.h>
#include <hip/hip_bf16.h>
#include <stdint.h>

// Problem constants (fixed by setup_inputs)
#define BB 8
#define NN 16384
#define GG 1024
#define SS 32
#define BN (BB*NN)          // 131072

// Output offsets (elements, float32)
#define OFF_SIDX 0
#define OFF_SN   8192
#define OFF_SXYZ 770048     // 8192 + 8192*31*3
#define OFF_ORD  794624     // + 24576
#define OFF_INV  827392     // + 32768

// Workspace offsets (bytes)
#define WS_SIDX 0                    // int[8192]
#define WS_KNN  32768                // int[8192*32] = 1 MB

typedef float v2f __attribute__((ext_vector_type(2)));

static __device__ __forceinline__ v2f vmin2(v2f a, v2f b) {
    v2f r; r.x = fminf(a.x, b.x); r.y = fminf(a.y, b.y); return r;
}
static __device__ __forceinline__ v2f vmax2(v2f a, v2f b) {
    v2f r; r.x = fmaxf(a.x, b.x); r.y = fmaxf(a.y, b.y); return r;
}

// DPP u32 max merge (fuses to v_max_u32_dpp). old=v, bound_ctrl=false =>
// lanes without a valid source keep v (idempotent merge).
template<int CTRL, int RM, int BM>
static __device__ __forceinline__ unsigned dpp_umax(unsigned v) {
    unsigned o = (unsigned)__builtin_amdgcn_update_dpp((int)v, (int)v, CTRL, RM, BM, false);
    return o > v ? o : v;
}

// DPP u64 min merge.
template<int CTRL, int RM, int BM>
static __device__ __forceinline__ uint64_t dpp_umin64(uint64_t v) {
    unsigned lo = (unsigned)v, hi = (unsigned)(v >> 32);
    unsigned olo = (unsigned)__builtin_amdgcn_update_dpp((int)lo, (int)lo, CTRL, RM, BM, false);
    unsigned ohi = (unsigned)__builtin_amdgcn_update_dpp((int)hi, (int)hi, CTRL, RM, BM, false);
    uint64_t o = ((uint64_t)ohi << 32) | olo;
    return o < v ? o : v;
}

// full-wave u64 min, result valid in lane 63
static __device__ __forceinline__ uint64_t wave_umin64(uint64_t v) {
    v = dpp_umin64<0x111, 0xf, 0xf>(v);   // row_shr:1
    v = dpp_umin64<0x112, 0xf, 0xf>(v);   // row_shr:2
    v = dpp_umin64<0x114, 0xf, 0xf>(v);   // row_shr:4
    v = dpp_umin64<0x118, 0xf, 0xf>(v);   // row_shr:8
    v = dpp_umin64<0x142, 0xa, 0xf>(v);   // row_bcast:15 -> rows 1,3
    v = dpp_umin64<0x143, 0xc, 0xf>(v);   // row_bcast:31 -> rows 2,3
    return v;
}

// broadcast u64 from (uniform) lane sl
static __device__ __forceinline__ uint64_t rdlane64(uint64_t v, int sl) {
    unsigned lo = (unsigned)__builtin_amdgcn_readlane((int)(unsigned)v, sl);
    unsigned hi = (unsigned)__builtin_amdgcn_readlane((int)(unsigned)(v >> 32), sl);
    return ((uint64_t)hi << 32) | lo;
}

// Monotone float->u32 map: preserves IEEE float ordering even for negatives
// (d2 = (cc+pp)-2dot can round to tiny negatives; numpy orders them lowest).
static __device__ __forceinline__ unsigned mono(float f) {
    unsigned u = __float_as_uint(f);
    return u ^ (unsigned)((((int)u) >> 31) | (int)0x80000000u);
}

// ---------------------------------------------------------------------------
// 1) FPS: one block/batch, 1024 thr, 16 pts/thread as 8 float2 pairs.
//    PREFETCH-HOIST: the per-step coord re-loads (L2-resident, 192KB/CU
//    working set >> L1) are issued at the TOP of the step, with the entire
//    reduction tail (tree, DPP, B1, block max, claim, B2, s_load q) between
//    issue and first use — hiding L2 latency under work that must happen
//    anyway. Update runs at the bottom once q is known. Reduction skeleton
//    R3/R6/R7/R9-validated: wave DPP value-max -> LDS -> block DPP max ->
//    block-max holders atomicMin packed p = t + e*1024 (numpy first-argmax).
// ---------------------------------------------------------------------------
__global__ __launch_bounds__(1024)
__attribute__((amdgpu_waves_per_eu(4, 4)))
void fps_kernel(const float* __restrict__ coord,
                int* __restrict__ ws_sidx,
                float* __restrict__ out) {
#pragma clang fp contract(off)
    const int b = blockIdx.x;
    const int t = threadIdx.x;
    const int base = b * NN;
    const int wave = t >> 6, lane = t & 63;

    // q0 = pts[0] (uniform scalar load)
    const float q0x = coord[3*base], q0y = coord[3*base+1], q0z = coord[3*base+2];

    // pair j covers point indices e=2j (x-slot) and e=2j+1 (y-slot), p = t + e*1024
    v2f dist[8];
#pragma unroll
    for (int j = 0; j < 8; j++) {
        int pA = t + (j << 11);
        int pB = pA + 1024;
        v2f px = (v2f){coord[3*(base+pA)  ], coord[3*(base+pB)  ]};
        v2f py = (v2f){coord[3*(base+pA)+1], coord[3*(base+pB)+1]};
        v2f pz = (v2f){coord[3*(base+pA)+2], coord[3*(base+pB)+2]};
        // dist vs q0 (== ref's first update: min(inf, d2) = d2), bit-exact
        v2f dx = px - (v2f){q0x,q0x};
        v2f dy = py - (v2f){q0y,q0y};
        v2f dz = pz - (v2f){q0z,q0z};
        dist[j] = (dx*dx + dy*dy) + dz*dz;
    }

    __shared__ unsigned wv[16];       // per-wave max bits
    __shared__ unsigned win[2];       // packed winner p, double-buffered by parity

    if (t == 0) {
        ws_sidx[b*GG] = base;                 // selection 0 = index 0
        out[OFF_SIDX + b*GG] = (float)base;
        win[0] = 0xffffffffu; win[1] = 0xffffffffu;
    }
    __syncthreads();

    for (int g = 1; g < GG; g++) {
        const int s = g & 1;
        // ---- PREFETCH coords for this step's update (no q dependency):
        //      issued here so L2 latency is hidden under the reduction tail
        v2f fx[8], fy[8], fz[8];
#pragma unroll
        for (int j = 0; j < 8; j++) {
            int pA = t + (j << 11);
            int pB = pA + 1024;
            fx[j] = (v2f){coord[3*(base+pA)  ], coord[3*(base+pB)  ]};
            fy[j] = (v2f){coord[3*(base+pA)+1], coord[3*(base+pB)+1]};
            fz[j] = (v2f){coord[3*(base+pA)+2], coord[3*(base+pB)+2]};
        }
        // ---- per-thread max of current dist (value only), pk tree
        //      (dists are sums of squares >= +0: u32 bit order == float order)
        v2f m01 = vmax2(dist[0], dist[1]);
        v2f m23 = vmax2(dist[2], dist[3]);
        v2f m45 = vmax2(dist[4], dist[5]);
        v2f m67 = vmax2(dist[6], dist[7]);
        v2f m07 = vmax2(vmax2(m01, m23), vmax2(m45, m67));
        float bvf = fmaxf(m07.x, m07.y);
        unsigned lb = __float_as_uint(bvf);   // local max as orderable bits
        // ---- wave max via DPP (value only; result in lane 63)
        unsigned r = lb;
        r = dpp_umax<0x111, 0xf, 0xf>(r);
        r = dpp_umax<0x112, 0xf, 0xf>(r);
        r = dpp_umax<0x114, 0xf, 0xf>(r);
        r = dpp_umax<0x118, 0xf, 0xf>(r);
        r = dpp_umax<0x142, 0xa, 0xf>(r);
        r = dpp_umax<0x143, 0xc, 0xf>(r);
        unsigned wmax = (unsigned)__builtin_amdgcn_readlane((int)r, 63);
        if (lane == 0) wv[wave] = wmax;
        __syncthreads();                      // B1: wv ready; win[s] reads of g-1 done
        if (t == 0) win[1 - s] = 0xffffffffu; // reset other slot for step g+1
        // ---- block max: 16 wave winners, 4-level DPP within rows of 16
        unsigned x = wv[lane & 15];
        x = dpp_umax<0x111, 0xf, 0xf>(x);
        x = dpp_umax<0x112, 0xf, 0xf>(x);
        x = dpp_umax<0x114, 0xf, 0xf>(x);
        x = dpp_umax<0x118, 0xf, 0xf>(x);
        unsigned bmax = (unsigned)__builtin_amdgcn_readlane((int)x, 15);
        // ---- claim: exact first-max index = min p, p = t + e*1024 (rare path)
        if (lb == bmax) {
            int e = 15;
#pragma unroll
            for (int jj = 15; jj >= 0; jj--) {
                float v = (jj & 1) ? dist[jj >> 1].y : dist[jj >> 1].x;
                if (__float_as_uint(v) == bmax) e = jj;
            }
            atomicMin(&win[s], (unsigned)(t + (e << 10)));
        }
        __syncthreads();                      // B2: winner resolved
        unsigned pw = win[s];
        int sp = __builtin_amdgcn_readfirstlane((int)pw);
        if (t == 0) {
            ws_sidx[b*GG + g] = base + sp;
            out[OFF_SIDX + b*GG + g] = (float)(base + sp);
        }
        // uniform (scalar) reload of winner coords
        float qx = coord[3*(base+sp)];
        float qy = coord[3*(base+sp)+1];
        float qz = coord[3*(base+sp)+2];
        // ---- update with PREFETCHED coords: dist = min(dist, |p-q|^2),
        //      bit-exact (no fma, left-assoc); seen by step g+1's argmax
        v2f qvx = (v2f){qx,qx}, qvy = (v2f){qy,qy}, qvz = (v2f){qz,qz};
#pragma unroll
        for (int j = 0; j < 8; j++) {
            v2f dx = fx[j] - qvx, dy = fy[j] - qvy, dz = fz[j] - qvz;
            v2f d  = (dx*dx + dy*dy) + dz*dz;
            dist[j] = vmin2(dist[j], d);
        }
    }
}

// ---------------------------------------------------------------------------
// 2) kNN top-32: one wave per center, no LDS. Per-lane TOP-2 cache of packed
//    keys (mono(d2)<<14 | p): the scattered rescan of the winner's stripe
//    runs only when the winner's cache is empty (~7/32 rounds). mono() makes
//    key order == (d2 float order, index) lex == stable top_k semantics.
// ---------------------------------------------------------------------------
__global__ __launch_bounds__(64) void knn_kernel(const float* __restrict__ coord,
                                                 const int* __restrict__ ws_sidx,
                                                 int* __restrict__ ws_knn) {
#pragma clang fp contract(off)
    const int c = blockIdx.x;             // center 0..8191
    const int l = threadIdx.x;            // lane 0..63
    const int b = c >> 10;
    const int base = b * NN;
    const int sg = ws_sidx[c];            // global center index
    const float cx = coord[3*sg], cy = coord[3*sg+1], cz = coord[3*sg+2];
    const float cc = (cx*cx + cy*cy) + cz*cz;

    // phase 1: per-lane two smallest keys over stripe {l + 64*j}
    uint64_t k1 = ~0ull, k2 = ~0ull;
#pragma unroll 4
    for (int j = 0; j < 256; j++) {
        int p = l + (j << 6);
        float x = coord[3*(base+p)], y = coord[3*(base+p)+1], z = coord[3*(base+p)+2];
        float pp  = (x*x + y*y) + z*z;
        float dot = (cx*x + cy*y) + cz*z;
        float d2  = (cc + pp) - 2.0f*dot;             // ref formula exactly
        uint64_t key = (((uint64_t)mono(d2)) << 14) | (unsigned)p;
        if (key < k1)      { k2 = k1; k1 = key; }
        else if (key < k2) { k2 = key; }
    }

    uint64_t m0 = 0, m1 = 0, m2 = 0, m3 = 0;          // consumed bits, my stripe
    uint64_t cur = k1, nxt = k2;
    bool have_nxt = true;
    int res_p = 0;
    for (int k = 0; k < SS; k++) {
        // global argmin over per-lane current minima (value, then index)
        uint64_t wmin = wave_umin64(cur);
        uint64_t bkey = rdlane64(wmin, 63);           // scalar winner key
        const int bp = (int)(bkey & 16383u);          // winner point (scalar)
        const int w  = bp & 63;                       // winner lane / stripe
        const int e  = bp >> 6;                       // element within stripe
        if (l == k) res_p = bp;                       // lane k keeps k-th neighbor
        bool need_rescan = false;
        if (l == w) {                                 // mark consumed
            uint64_t bit = 1ull << (e & 63);
            int word = e >> 6;
            if      (word == 0) m0 |= bit;
            else if (word == 1) m1 |= bit;
            else if (word == 2) m2 |= bit;
            else                m3 |= bit;
            if (have_nxt) { cur = nxt; have_nxt = false; }
            else need_rescan = true;
        }
        if (__ballot(need_rescan)) {                  // wave-uniform rare path
            uint64_t w0 = rdlane64(m0, w), w1 = rdlane64(m1, w),
                     w2 = rdlane64(m2, w), w3 = rdlane64(m3, w);
            uint64_t best = ~0ull;
#pragma unroll
            for (int m = 0; m < 4; m++) {
                int e2 = l + (m << 6);
                uint64_t mw = (m == 0) ? w0 : ((m == 1) ? w1 : ((m == 2) ? w2 : w3));
                int p2 = w + (e2 << 6);
                float x = coord[3*(base+p2)], y = coord[3*(base+p2)+1], z = coord[3*(base+p2)+2];
                float pp  = (x*x + y*y) + z*z;
                float dot = (cx*x + cy*y) + cz*z;
                float d2  = (cc + pp) - 2.0f*dot;     // bit-exact recompute
                uint64_t key = (((uint64_t)mono(d2)) << 14) | (unsigned)p2;
                bool cons = (mw >> l) & 1ull;
                if (!cons && key < best) best = key;
            }
            best = wave_umin64(best);
            uint64_t rk = rdlane64(best, 63);
            if (l == w) cur = rk;                     // refreshed stripe-min
        }
    }
    if (l < SS) ws_knn[c * SS + l] = res_p;           // local point index
}

// ---------------------------------------------------------------------------
// 3) s_xyz gather
// ---------------------------------------------------------------------------
__global__ void sxyz_kernel(const float* __restrict__ coord,
                            const int* __restrict__ ws_sidx,
                            float* __restrict__ out) {
    int t = blockIdx.x * blockDim.x + threadIdx.x;
    if (t < 8192*3) {
        int i = t / 3, cmp = t - 3*i;
        out[OFF_SXYZ + t] = coord[3*ws_sidx[i] + cmp];
    }
}

// ---------------------------------------------------------------------------
// 4) s_n = coord[knn[1..31]] - center
// ---------------------------------------------------------------------------
__global__ void sn_kernel(const float* __restrict__ coord,
                          const int* __restrict__ ws_sidx,
                          const int* __restrict__ ws_knn,
                          float* __restrict__ out) {
#pragma clang fp contract(off)
    int t = blockIdx.x * blockDim.x + threadIdx.x;
    if (t < 8192*31*3) {
        int cmp = t % 3; int rem = t / 3;
        int j = rem % 31; int i = rem / 31;
        int b = i >> 10;
        int nb = ws_knn[i*SS + j + 1];                // skip neighbor 0 (self)
        int gidx = b*NN + nb;
        float v = coord[3*gidx + cmp] - coord[3*ws_sidx[i] + cmp];
        out[OFF_SN + t] = v;
    }
}

// ---------------------------------------------------------------------------
// 5) stable argsort per code row: bitonic sort of (code<<13 | idx) in LDS
// ---------------------------------------------------------------------------
__global__ __launch_bounds__(1024) void sort_kernel(const int* __restrict__ ser,
                                                    const int* __restrict__ ws_sidx,
                                                    float* __restrict__ out) {
    __shared__ uint64_t keys[8192];                   // 64 KB
    const int r = blockIdx.x, t = threadIdx.x;
#pragma unroll
    for (int s = 0; s < 8; s++) {
        int i = t + (s << 10);
        uint32_t code = (uint32_t)ser[r * BN + ws_sidx[i]];   // < 2^30
        keys[i] = ((uint64_t)code << 13) | (uint32_t)i;       // unique keys => stable
    }
    __syncthreads();
    for (int k2 = 2; k2 <= 8192; k2 <<= 1) {
        for (int j = k2 >> 1; j > 0; j >>= 1) {
#pragma unroll 2
            for (int s = 0; s < 8; s++) {
                int i = t + (s << 10);
                int ixj = i ^ j;
                if (ixj > i) {
                    uint64_t a = keys[i], bq = keys[ixj];
                    bool up = ((i & k2) == 0);
                    if ((a > bq) == up) { keys[i] = bq; keys[ixj] = a; }
                }
            }
            __syncthreads();
        }
    }
    for (int s = 0; s < 8; s++) {
        int k = t + (s << 10);
        uint64_t key = keys[k];
        int i = (int)(key & 8191u);
        out[OFF_ORD + r*8192 + k] = (float)i;
        out[OFF_INV + r*8192 + i] = (float)k;
    }
}

// ---------------------------------------------------------------------------
extern "C" void kernel_launch(void* const* d_in, const int* in_sizes, int n_in,
                              void* d_out, int out_size, void* d_ws, size_t ws_size,
                              hipStream_t stream) {
    const float* coord = (const float*)d_in[0];
    const int*   ser   = (const int*)d_in[1];
    float* out = (float*)d_out;
    char* ws = (char*)d_ws;
    int* ws_sidx = (int*)(ws + WS_SIDX);
    int* ws_knn  = (int*)(ws + WS_KNN);

    hipLaunchKernelGGL(fps_kernel,  dim3(BB),   dim3(1024), 0, stream, coord, ws_sidx, out);
    hipLaunchKernelGGL(knn_kernel,  dim3(8192), dim3(64),   0, stream, coord, ws_sidx, ws_knn);
    hipLaunchKernelGGL(sxyz_kernel, dim3(96),   dim3(256),  0, stream, coord, ws_sidx, out);
    hipLaunchKernelGGL(sn_kernel,   dim3(2976), dim3(256),  0, stream, coord, ws_sidx, ws_knn, out);
    hipLaunchKernelGGL(sort_kernel, dim3(4),    dim3(1024), 0, stream, ser, ws_sidx, out);
}